// Round 12
// baseline (313.288 us; speedup 1.0000x reference)
//
#include <hip/hip_runtime.h>
#include <math.h>
#include <limits.h>

// RelativeBucketedTimeAndPositionBasedBias — B=16, N=2048, NUM_BUCKETS=128
// out[b,i,j] = pos_w[N-1 + j - i] + ts_w[bucket(b,i,j)]
//   diff = ext[b,i+1] - ext[b,j]; m = max(|diff·causal|, 1)  (integer, < 2^24)
//
// R12 = R11 retry (compile fix: removed misplaced #pragma clang fp).
// Hypothesis: ref = jax/XLA-CPU recompute. XLA AlgebraicSimplifier rewrites
// divide-by-constant into multiply-by-reciprocal (default, not fast-math):
//   bucket = clip(trunc( RN_f32( log32(m) * RN_f32(1/0.301f) ) ), 0, 128)
// All 6 accurate-f32-log variants tried gave bit-identical output (0.0276) —
// log values at decisive integers are CR; the remaining degree of freedom is
// the division step. trunc(RN(CRlog32(m))*recip) is monotone in integer m, so
// we build exact integer thresholds T[k] on device and resolve buckets with
// pure integer compares (hw-log estimate +-1, two LDS compares) — hot loop has
// no float sensitivity.

#define NN 2048
#define BLOCK 256
#define NTHR 130   // thresholds T[0..129]

__global__ void build_thresholds_kernel(int* __restrict__ T) {
    const int k = threadIdx.x;
    if (k >= NTHR) return;
    // recip as XLA folds it: f32 reciprocal of the f32 literal 0.301.
    // (computed in f64, rounded once to f32 — no contraction hazard here:
    //  the only FP ops below are a log() call, one isolated mul, a compare)
    const float recip = (float)(1.0 / (double)0.301f);   // RN_f32(3.32225914...)
    // T[k] = min { m >= 1 : (int)( RN_f32(log(m)) * recip ) >= k }
    double est = exp(0.301 * (double)k);
    if (est > 2.0e9) { T[k] = INT_MAX; return; }
    long long lo = (long long)floor(est) - 160;
    if (lo < 1) lo = 1;
    int result = INT_MAX;
    for (long long m = lo; m < lo + 480; ++m) {
        float lg = (float)log((double)m);   // CR f32 log of integer m
        float q = lg * recip;               // f32 RN multiply (the XLA rewrite)
        if ((int)q >= k) { result = (int)m; break; }
    }
    T[k] = result;
}

__device__ __forceinline__ float bias_elem(int t_next, int tj, int j, int i,
                                           const float* __restrict__ s_tsw,
                                           const int* __restrict__ s_T,
                                           float ts0, float pv) {
    if (j > i) return pv + ts0;            // non-causal: td=0 -> bucket 0
    int mi = t_next - tj;                  // >= 0 (rows sorted)
    if (mi < 1) mi = 1;                    // max(|td|, 1)
    // estimate: log(m)*recip = log2(m) * (ln2*recip); error << 0.5 bucket
    int b0 = (int)(__log2f((float)mi) * 2.3028146f);
    b0 = b0 < 0 ? 0 : (b0 > 128 ? 128 : b0);
    // exact correction via monotone integer thresholds
    int b = b0 + (mi >= s_T[b0 + 1] ? 1 : 0) - (mi < s_T[b0] ? 1 : 0);
    return pv + s_tsw[b];
}

__global__ __launch_bounds__(BLOCK) void hstu_bias_kernel(
    const int* __restrict__ ts,      // [B, N] int32, sorted per row
    const float* __restrict__ ts_w,  // [129]
    const float* __restrict__ pos_w, // [2N-1]
    const int* __restrict__ T,       // [130] thresholds
    float* __restrict__ out)         // [B, N, N]
{
    __shared__ float s_tsw[129];
    __shared__ int s_T[NTHR];
    const int tid = threadIdx.x;
    if (tid < 129) s_tsw[tid] = ts_w[tid];
    if (tid < NTHR) s_T[tid] = T[tid];
    __syncthreads();

    const int row = blockIdx.x;          // b*N + i
    const int b = row >> 11;
    const int i = row & (NN - 1);
    const int* __restrict__ ts_row = ts + b * NN;
    const int t_next = ts_row[(i < NN - 1) ? (i + 1) : (NN - 1)];  // ext[b,i+1]
    const float* __restrict__ pw = pos_w + (NN - 1 - i);           // pw[j] = pos_w[N-1+j-i]
    float4* __restrict__ out4 = (float4*)(out + (size_t)row * NN);
    const float ts0 = s_tsw[0];

#pragma unroll
    for (int it = 0; it < 2; ++it) {
        const int j4 = tid + it * BLOCK;
        const int j = j4 * 4;
        const int4 tj = *(const int4*)(ts_row + j);  // aligned 16B
        const float pv0 = pw[j + 0];
        const float pv1 = pw[j + 1];
        const float pv2 = pw[j + 2];
        const float pv3 = pw[j + 3];

        float4 r;
        r.x = bias_elem(t_next, tj.x, j + 0, i, s_tsw, s_T, ts0, pv0);
        r.y = bias_elem(t_next, tj.y, j + 1, i, s_tsw, s_T, ts0, pv1);
        r.z = bias_elem(t_next, tj.z, j + 2, i, s_tsw, s_T, ts0, pv2);
        r.w = bias_elem(t_next, tj.w, j + 3, i, s_tsw, s_T, ts0, pv3);
        out4[j4] = r;
    }
}

extern "C" void kernel_launch(void* const* d_in, const int* in_sizes, int n_in,
                              void* d_out, int out_size, void* d_ws, size_t ws_size,
                              hipStream_t stream) {
    const int* ts = (const int*)d_in[0];        // all_timestamps [16,2048]
    const float* ts_w = (const float*)d_in[1];  // [129]
    const float* pos_w = (const float*)d_in[2]; // [4095]
    float* out = (float*)d_out;                 // [16,2048,2048] f32
    int* T = (int*)d_ws;                        // 130 ints of scratch

    build_thresholds_kernel<<<1, 256, 0, stream>>>(T);

    const int B = 16;
    hstu_bias_kernel<<<dim3(B * NN), dim3(BLOCK), 0, stream>>>(ts, ts_w, pos_w, T, out);
}

// Round 13
// 280.598 us; speedup vs baseline: 1.1165x; 1.1165x over previous
//
#include <hip/hip_runtime.h>
#include <math.h>
#include <limits.h>

// RelativeBucketedTimeAndPositionBasedBias — B=16, N=2048, NUM_BUCKETS=128
// out[b,i,j] = pos_w[N-1 + j - i] + ts_w[bucket(b,i,j)]
//   diff = ext[b,i+1] - ext[b,j]; m = max(|diff·causal|, 1)  (integer, < 2^24)
//
// VERIFIED BIT-EXACT (R12, absmax=0): ref pipeline is
//   bucket = clip(trunc( RN_f32( log32(m) * RN_f32(1/0.301f) ) ), 0, 128)
// (XLA AlgebraicSimplifier divide->multiply-by-reciprocal rewrite).
// Buckets are a monotone step function of integer m; we build exact integer
// thresholds T[k] on device, then resolve buckets with a hw-log estimate (+-1)
// corrected by two integer compares. DO NOT change the threshold pipeline.
//
// R13 perf fix: R12's <<<1,256>>> serial threshold build (130 threads x up to
// 480 serial f64 log() calls on ONE CU) cost ~250 us of the 313 us total.
// Parallelized: 130 blocks x 512 threads, one candidate per thread (boundary
// uncertainty is +-~16 integers; 512-window centered is safe), LDS atomicMin.

#define NN 2048
#define BLOCK 256
#define NTHR 130   // thresholds T[0..129]

__global__ void build_thresholds_kernel(int* __restrict__ T) {
    const int k = blockIdx.x;              // 0..129
    __shared__ int s_min;
    if (threadIdx.x == 0) s_min = INT_MAX;
    __syncthreads();

    const float recip = (float)(1.0 / (double)0.301f);   // RN_f32(1/f32(0.301))
    const double est = exp(0.301 * (double)k);
    if (est > 2.0e9) {
        if (threadIdx.x == 0) T[k] = INT_MAX;
        return;
    }
    long long lo = (long long)floor(est) - 256;
    if (lo < 1) lo = 1;
    const long long m = lo + (long long)threadIdx.x;     // one candidate/thread
    const float lg = (float)log((double)m);              // CR f32 log of integer m
    const float q = lg * recip;                          // f32 RN multiply
    if ((int)q >= k) atomicMin(&s_min, (int)m);          // monotone predicate
    __syncthreads();
    if (threadIdx.x == 0) T[k] = s_min;
}

__device__ __forceinline__ float bias_elem(int t_next, int tj, int j, int i,
                                           const float* __restrict__ s_tsw,
                                           const int* __restrict__ s_T,
                                           float ts0, float pv) {
    if (j > i) return pv + ts0;            // non-causal: td=0 -> bucket 0
    int mi = t_next - tj;                  // >= 0 (rows sorted)
    if (mi < 1) mi = 1;                    // max(|td|, 1)
    // estimate: log(m)*recip = log2(m) * (ln2*recip); error << 0.5 bucket
    int b0 = (int)(__log2f((float)mi) * 2.3028146f);
    b0 = b0 < 0 ? 0 : (b0 > 128 ? 128 : b0);
    // exact correction via monotone integer thresholds
    int b = b0 + (mi >= s_T[b0 + 1] ? 1 : 0) - (mi < s_T[b0] ? 1 : 0);
    return pv + s_tsw[b];
}

__global__ __launch_bounds__(BLOCK) void hstu_bias_kernel(
    const int* __restrict__ ts,      // [B, N] int32, sorted per row
    const float* __restrict__ ts_w,  // [129]
    const float* __restrict__ pos_w, // [2N-1]
    const int* __restrict__ T,       // [130] thresholds
    float* __restrict__ out)         // [B, N, N]
{
    __shared__ float s_tsw[129];
    __shared__ int s_T[NTHR];
    const int tid = threadIdx.x;
    if (tid < 129) s_tsw[tid] = ts_w[tid];
    if (tid < NTHR) s_T[tid] = T[tid];
    __syncthreads();

    const int row = blockIdx.x;          // b*N + i
    const int b = row >> 11;
    const int i = row & (NN - 1);
    const int* __restrict__ ts_row = ts + b * NN;
    const int t_next = ts_row[(i < NN - 1) ? (i + 1) : (NN - 1)];  // ext[b,i+1]
    const float* __restrict__ pw = pos_w + (NN - 1 - i);           // pw[j] = pos_w[N-1+j-i]
    float4* __restrict__ out4 = (float4*)(out + (size_t)row * NN);
    const float ts0 = s_tsw[0];

#pragma unroll
    for (int it = 0; it < 2; ++it) {
        const int j4 = tid + it * BLOCK;
        const int j = j4 * 4;
        const int4 tj = *(const int4*)(ts_row + j);  // aligned 16B
        const float pv0 = pw[j + 0];
        const float pv1 = pw[j + 1];
        const float pv2 = pw[j + 2];
        const float pv3 = pw[j + 3];

        float4 r;
        r.x = bias_elem(t_next, tj.x, j + 0, i, s_tsw, s_T, ts0, pv0);
        r.y = bias_elem(t_next, tj.y, j + 1, i, s_tsw, s_T, ts0, pv1);
        r.z = bias_elem(t_next, tj.z, j + 2, i, s_tsw, s_T, ts0, pv2);
        r.w = bias_elem(t_next, tj.w, j + 3, i, s_tsw, s_T, ts0, pv3);
        out4[j4] = r;
    }
}

extern "C" void kernel_launch(void* const* d_in, const int* in_sizes, int n_in,
                              void* d_out, int out_size, void* d_ws, size_t ws_size,
                              hipStream_t stream) {
    const int* ts = (const int*)d_in[0];        // all_timestamps [16,2048]
    const float* ts_w = (const float*)d_in[1];  // [129]
    const float* pos_w = (const float*)d_in[2]; // [4095]
    float* out = (float*)d_out;                 // [16,2048,2048] f32
    int* T = (int*)d_ws;                        // 130 ints of scratch

    build_thresholds_kernel<<<dim3(NTHR), dim3(512), 0, stream>>>(T);

    const int B = 16;
    hstu_bias_kernel<<<dim3(B * NN), dim3(BLOCK), 0, stream>>>(ts, ts_w, pos_w, T, out);
}